// Round 1
// baseline (305.371 us; speedup 1.0000x reference)
//
#include <hip/hip_runtime.h>
#include <math.h>

#define NS 96
#define SM1 95
#define NC 32
#define REPS 1e-10f

// One ray per block of 256 threads.
__global__ __launch_bounds__(256) void raymarch_main(
    const float* __restrict__ colors,     // [rays, 96, 32]
    const float* __restrict__ densities,  // [rays, 96]
    const float* __restrict__ depths,     // [rays, 96]
    float* __restrict__ out_rgb,          // [rays, 32]
    float* __restrict__ out_depth,        // [rays]  (unclipped, nan->inf)
    float* __restrict__ out_w,            // [rays, 95]
    float* __restrict__ out_alpha,        // [rays, 95]
    float* __restrict__ out_wbg,          // [rays]
    float* __restrict__ ws_d0,            // [rays] first depth per ray
    float* __restrict__ ws_d1)            // [rays] last depth per ray
{
    const int ray = blockIdx.x;
    const int tid = threadIdx.x;

    __shared__ float s_dep[NS];
    __shared__ float s_den[NS];
    __shared__ float s_alpha[SM1];
    __shared__ float s_oma[SM1];
    __shared__ float s_w[SM1];
    __shared__ float s_coeff[NS];
    __shared__ float s_red[256 * 4];

    // Pre-issue the heavy color loads so HBM latency overlaps the scan.
    const float4* col4 = (const float4*)(colors + (size_t)ray * NS * NC);
    float4 v0 = col4[tid];
    float4 v1 = col4[256 + tid];
    float4 v2 = col4[512 + tid];

    const float* dep = depths + (size_t)ray * NS;
    const float* den = densities + (size_t)ray * NS;

    if (tid < NS) {
        s_dep[tid] = dep[tid];
        s_den[tid] = den[tid];
    }
    __syncthreads();

    if (tid < SM1) {
        float dm = 0.5f * (s_den[tid] + s_den[tid + 1]) - 1.0f;
        // softplus = max(x,0) + log1p(exp(-|x|))   (jax.nn.softplus)
        float sp = fmaxf(dm, 0.0f) + log1pf(expf(-fabsf(dm)));
        float dd = sp * (s_dep[tid + 1] - s_dep[tid]);
        float a = 1.0f - expf(-dd);
        s_alpha[tid] = a;
        s_oma[tid] = 1.0f - a + REPS;
        out_alpha[(size_t)ray * SM1 + tid] = a;
    }
    __syncthreads();

    if (tid == 0) {
        float T = 1.0f, wsum = 0.0f, dsum = 0.0f;
        #pragma unroll 5
        for (int i = 0; i < SM1; ++i) {
            float w = s_alpha[i] * T;
            s_w[i] = w;
            wsum += w;
            dsum += w * (0.5f * (s_dep[i] + s_dep[i + 1]));
            T *= s_oma[i];
        }
        out_wbg[ray] = T;
        float cd = dsum / wsum;
        if (cd != cd) cd = __builtin_inff();  // NaN -> inf (clip happens in kernel 2)
        out_depth[ray] = cd;
        ws_d0[ray] = s_dep[0];
        ws_d1[ray] = s_dep[NS - 1];
    }
    __syncthreads();

    if (tid < NS) {
        float wprev = (tid >= 1)  ? s_w[tid - 1] : 0.0f;
        float wcur  = (tid < SM1) ? s_w[tid]     : 0.0f;
        s_coeff[tid] = 0.5f * (wprev + wcur);
    }
    if (tid < SM1) {
        out_w[(size_t)ray * SM1 + tid] = s_w[tid];
    }
    __syncthreads();

    // Accumulate coeff[s] * colors[s][c]; thread t handles float4 indices
    // t, 256+t, 512+t  (sample s = idx>>3, channel group = idx&7).
    float4 acc;
    {
        float c0 = s_coeff[tid >> 3];
        float c1 = s_coeff[(256 + tid) >> 3];
        float c2 = s_coeff[(512 + tid) >> 3];
        acc.x = fmaf(c0, v0.x, fmaf(c1, v1.x, c2 * v2.x));
        acc.y = fmaf(c0, v0.y, fmaf(c1, v1.y, c2 * v2.y));
        acc.z = fmaf(c0, v0.z, fmaf(c1, v1.z, c2 * v2.z));
        acc.w = fmaf(c0, v0.w, fmaf(c1, v1.w, c2 * v2.w));
    }
    s_red[tid * 4 + 0] = acc.x;
    s_red[tid * 4 + 1] = acc.y;
    s_red[tid * 4 + 2] = acc.z;
    s_red[tid * 4 + 3] = acc.w;
    __syncthreads();

    if (tid < NC) {
        // channel tid; partials live at s_red[m*32 + tid], m = 0..31
        float sum = 0.0f;
        #pragma unroll
        for (int m = 0; m < 32; ++m) {
            sum += s_red[m * 32 + tid];
        }
        out_rgb[(size_t)ray * NC + tid] = 2.0f * sum - 1.0f;
    }
}

// Grid-wide min/max of depths (via sorted-ray endpoints), then clip depth.
__global__ __launch_bounds__(256) void raymarch_finalize(
    const float* __restrict__ ws_d0,
    const float* __restrict__ ws_d1,
    float* __restrict__ out_depth,
    int rays)
{
    __shared__ float s_mn[256];
    __shared__ float s_mx[256];
    const int tid = threadIdx.x;

    float mn = __builtin_inff();
    float mx = -__builtin_inff();
    for (int r = tid; r < rays; r += 256) {
        mn = fminf(mn, ws_d0[r]);
        mx = fmaxf(mx, ws_d1[r]);
    }
    s_mn[tid] = mn;
    s_mx[tid] = mx;
    __syncthreads();
    for (int off = 128; off > 0; off >>= 1) {
        if (tid < off) {
            s_mn[tid] = fminf(s_mn[tid], s_mn[tid + off]);
            s_mx[tid] = fmaxf(s_mx[tid], s_mx[tid + off]);
        }
        __syncthreads();
    }
    const float dmin = s_mn[0];
    const float dmax = s_mx[0];

    const int r = blockIdx.x * 256 + tid;
    if (r < rays) {
        float cd = out_depth[r];
        cd = fminf(fmaxf(cd, dmin), dmax);  // clip(inf) -> dmax, matches jnp
        out_depth[r] = cd;
    }
}

extern "C" void kernel_launch(void* const* d_in, const int* in_sizes, int n_in,
                              void* d_out, int out_size, void* d_ws, size_t ws_size,
                              hipStream_t stream) {
    const float* colors    = (const float*)d_in[0];
    const float* densities = (const float*)d_in[1];
    const float* depths    = (const float*)d_in[2];

    const int rays = in_sizes[2] / NS;  // B*R = 16384

    float* out = (float*)d_out;
    float* out_rgb   = out;                                   // rays*32
    float* out_depth = out_rgb + (size_t)rays * NC;           // rays
    float* out_w     = out_depth + rays;                      // rays*95
    float* out_alpha = out_w + (size_t)rays * SM1;            // rays*95
    float* out_wbg   = out_alpha + (size_t)rays * SM1;        // rays

    float* ws    = (float*)d_ws;
    float* ws_d0 = ws;
    float* ws_d1 = ws + rays;

    raymarch_main<<<rays, 256, 0, stream>>>(
        colors, densities, depths,
        out_rgb, out_depth, out_w, out_alpha, out_wbg, ws_d0, ws_d1);

    raymarch_finalize<<<(rays + 255) / 256, 256, 0, stream>>>(
        ws_d0, ws_d1, out_depth, rays);
}